// Round 3
// baseline (401.291 us; speedup 1.0000x reference)
//
#include <hip/hip_runtime.h>

// Analysis filters
__device__ __constant__ float H0[8] = { 0.0322231f, -0.01260397f, -0.09921954f,  0.2978578f,
                                        0.80373875f, 0.49761867f, -0.02963553f, -0.07576571f};
__device__ __constant__ float H1[8] = { 0.07576571f, -0.02963553f, -0.49761867f, 0.80373875f,
                                       -0.2978578f, -0.09921954f,  0.01260397f,  0.0322231f};
// Synthesis filters g0 = reverse(h0), g1 = reverse(h1)
__device__ __constant__ float G0[8] = {-0.07576571f, -0.02963553f,  0.49761867f, 0.80373875f,
                                        0.2978578f,  -0.09921954f, -0.01260397f, 0.0322231f};
__device__ __constant__ float G1[8] = { 0.0322231f,   0.01260397f, -0.09921954f, -0.2978578f,
                                        0.80373875f, -0.49761867f, -0.02963553f, 0.07576571f};

// ---------------------------------------------------------------------------
// Forward DWT, 2x2-output-tiled + separable (unchanged from R1).
// ---------------------------------------------------------------------------
template<int HIN>
__global__ __launch_bounds__(256) void fwd_dwt(const float* __restrict__ in,
                                               float* __restrict__ oLL, float* __restrict__ oLH,
                                               float* __restrict__ oHL, float* __restrict__ oHH)
{
    constexpr int OH = HIN / 2;
    constexpr int TQ = OH / 2;
    const int tid = threadIdx.x;
    const int c = tid & 63;
    const int s = blockIdx.x * 4 + (tid >> 6);
    const int j = s % TQ;
    const int i = (s / TQ) % TQ;
    const int b = s / (TQ * TQ);

    float acc[2][2][4];
#pragma unroll
    for (int a = 0; a < 2; ++a)
#pragma unroll
        for (int d = 0; d < 2; ++d)
#pragma unroll
            for (int k = 0; k < 4; ++k) acc[a][d][k] = 0.f;

    const int iw0 = 4 * j - 3;
#pragma unroll
    for (int r = 0; r < 10; ++r) {
        const int ih = 4 * i + r - 3;
        if ((unsigned)ih < (unsigned)HIN) {
            const float* row = in + ((b * HIN + ih) * HIN) * 64 + c;
            float xv[10];
#pragma unroll
            for (int v = 0; v < 10; ++v) {
                const int iw = iw0 + v;
                xv[v] = ((unsigned)iw < (unsigned)HIN) ? row[iw * 64] : 0.f;
            }
            float h00 = 0.f, h01 = 0.f, h10 = 0.f, h11 = 0.f;
#pragma unroll
            for (int v = 0; v < 8; ++v) {
                h00 += H0[v] * xv[v];
                h10 += H1[v] * xv[v];
                h01 += H0[v] * xv[v + 2];
                h11 += H1[v] * xv[v + 2];
            }
#pragma unroll
            for (int ii = 0; ii < 2; ++ii) {
                const int u = r - 2 * ii;
                if (0 <= u && u < 8) {
                    const float a0 = H0[u], a1 = H1[u];
                    acc[ii][0][0] += a0 * h00;
                    acc[ii][0][1] += a0 * h10;
                    acc[ii][0][2] += a1 * h00;
                    acc[ii][0][3] += a1 * h10;
                    acc[ii][1][0] += a0 * h01;
                    acc[ii][1][1] += a0 * h11;
                    acc[ii][1][2] += a1 * h01;
                    acc[ii][1][3] += a1 * h11;
                }
            }
        }
    }

#pragma unroll
    for (int ii = 0; ii < 2; ++ii)
#pragma unroll
        for (int jj = 0; jj < 2; ++jj) {
            const int oh = 2 * i + ii, ow = 2 * j + jj;
            const int oidx = ((b * OH + oh) * OH + ow) * 64 + c;
            oLL[oidx] = acc[ii][jj][0];
            oLH[oidx] = acc[ii][jj][1];
            oHL[oidx] = acc[ii][jj][2];
            oHH[oidx] = acc[ii][jj][3];
        }
}

// ---------------------------------------------------------------------------
// Local conv v2: out[b,h,w,o] = sum_i t[b,h,w,i] * W[i,o,w,h]
// Grid (HD, 64/OG, nz): 8 o per block -> 2x blocks vs R1 (6 blocks/CU).
// All loads of an i4-chunk (BJ act float4 + 4*OG weight scalars) are batched
// into registers before the FMAs -> ~36 outstanding loads/thread.
// Weight loads: lane=h -> coalesced 256B; each weight element fetched once
// from HBM (o partitions across blocks; bg-wave duplicates hit L2).
// ---------------------------------------------------------------------------
template<int HD, int BJ, int OG>
__global__ __launch_bounds__(256) void local_conv(
    const float* __restrict__ t0, const float* __restrict__ t1,
    const float* __restrict__ t2, const float* __restrict__ t3,
    const float* __restrict__ w0, const float* __restrict__ w1,
    const float* __restrict__ w2, const float* __restrict__ w3,
    float* __restrict__ o0, float* __restrict__ o1,
    float* __restrict__ o2, float* __restrict__ o3)
{
    const int z = blockIdx.z;
    const float* tin = (z == 0) ? t0 : (z == 1) ? t1 : (z == 2) ? t2 : t3;
    const float* wgt = (z == 0) ? w0 : (z == 1) ? w1 : (z == 2) ? w2 : w3;
    float*       out = (z == 0) ? o0 : (z == 1) ? o1 : (z == 2) ? o2 : o3;

    const int w   = blockIdx.x;
    const int og  = blockIdx.y;          // group of OG outputs
    const int tid = threadIdx.x;
    const int h   = tid % HD;
    const int bg  = tid / HD;            // 256/HD groups of BJ batches
    constexpr int WH = HD * HD;

    float acc[BJ][OG];
#pragma unroll
    for (int j = 0; j < BJ; ++j)
#pragma unroll
        for (int oo = 0; oo < OG; ++oo) acc[j][oo] = 0.f;

    const float* wbase = wgt + (og * OG) * WH + w * HD + h;

    for (int i4 = 0; i4 < 16; ++i4) {
        // ---- load phase (no FMAs in between) ----
        float4 tv[BJ];
#pragma unroll
        for (int j = 0; j < BJ; ++j) {
            const int b = bg * BJ + j;
            tv[j] = *(const float4*)(tin + ((b * HD + h) * HD + w) * 64 + i4 * 4);
        }
        float wv[4][OG];
#pragma unroll
        for (int di = 0; di < 4; ++di) {
            const float* wp = wbase + ((i4 * 4 + di) * 64) * WH;
#pragma unroll
            for (int oo = 0; oo < OG; ++oo)
                wv[di][oo] = wp[oo * WH];
        }
        // ---- compute phase ----
#pragma unroll
        for (int di = 0; di < 4; ++di)
#pragma unroll
            for (int oo = 0; oo < OG; ++oo)
#pragma unroll
                for (int j = 0; j < BJ; ++j) {
                    const float tj = ((const float*)&tv[j])[di];
                    acc[j][oo] += tj * wv[di][oo];
                }
    }

#pragma unroll
    for (int j = 0; j < BJ; ++j) {
        const int b = bg * BJ + j;
        float* op = out + ((b * HD + h) * HD + w) * 64 + og * OG;
#pragma unroll
        for (int o4 = 0; o4 < OG / 4; ++o4) {
            float4 v = make_float4(acc[j][o4 * 4 + 0], acc[j][o4 * 4 + 1],
                                   acc[j][o4 * 4 + 2], acc[j][o4 * 4 + 3]);
            *(float4*)(op + o4 * 4) = v;
        }
    }
}

// ---------------------------------------------------------------------------
// Inverse DWT, 2x2-output-tiled + separable (unchanged from R1).
// ---------------------------------------------------------------------------
template<int HOUT>
__global__ __launch_bounds__(256) void inv_dwt(const float* __restrict__ yLL,
                                               const float* __restrict__ yLH,
                                               const float* __restrict__ yHL,
                                               const float* __restrict__ yHH,
                                               float* __restrict__ out)
{
    constexpr int HS = HOUT / 2;
    const int tid = threadIdx.x;
    const int c = tid & 63;
    const int s = blockIdx.x * 4 + (tid >> 6);
    const int j = s % HS;
    const int i = (s / HS) % HS;
    const int b = s / (HS * HS);

    float Pe[4] = {0.f, 0.f, 0.f, 0.f}, Po[4] = {0.f, 0.f, 0.f, 0.f};
    float Qe[4] = {0.f, 0.f, 0.f, 0.f}, Qo[4] = {0.f, 0.f, 0.f, 0.f};

#pragma unroll
    for (int ku = 0; ku < 4; ++ku) {
        const int m = i - 1 + ku;
        if ((unsigned)m < (unsigned)HS) {
            const float a0e = G0[1 + 2 * ku], a0o = G0[2 * ku];
            const float a1e = G1[1 + 2 * ku], a1o = G1[2 * ku];
            const int rowoff = (b * HS + m) * HS;
#pragma unroll
            for (int kv = 0; kv < 4; ++kv) {
                const int n = j - 1 + kv;
                if ((unsigned)n < (unsigned)HS) {
                    const int idx = (rowoff + n) * 64 + c;
                    const float yll = yLL[idx], ylh = yLH[idx];
                    const float yhl = yHL[idx], yhh = yHH[idx];
                    Pe[kv] += a0e * yll + a1e * yhl;
                    Po[kv] += a0o * yll + a1o * yhl;
                    Qe[kv] += a0e * ylh + a1e * yhh;
                    Qo[kv] += a0o * ylh + a1o * yhh;
                }
            }
        }
    }

    float o00 = 0.f, o01 = 0.f, o10 = 0.f, o11 = 0.f;
#pragma unroll
    for (int kv = 0; kv < 4; ++kv) {
        const float b0e = G0[1 + 2 * kv], b0o = G0[2 * kv];
        const float b1e = G1[1 + 2 * kv], b1o = G1[2 * kv];
        o00 += b0e * Pe[kv] + b1e * Qe[kv];
        o01 += b0o * Pe[kv] + b1o * Qe[kv];
        o10 += b0e * Po[kv] + b1e * Qo[kv];
        o11 += b0o * Po[kv] + b1o * Qo[kv];
    }

    const int h0 = 2 * i, w0 = 2 * j;
    const int base = ((b * HOUT + h0) * HOUT + w0) * 64 + c;
    out[base] = o00;
    out[base + 64] = o01;
    out[base + HOUT * 64] = o10;
    out[base + HOUT * 64 + 64] = o11;
}

// ---------------------------------------------------------------------------
extern "C" void kernel_launch(void* const* d_in, const int* in_sizes, int n_in,
                              void* d_out, int out_size, void* d_ws, size_t ws_size,
                              hipStream_t stream)
{
    const float* x    = (const float*)d_in[0];
    const float* wLL  = (const float*)d_in[1];
    const float* wLH0 = (const float*)d_in[2];
    const float* wHL0 = (const float*)d_in[3];
    const float* wHH0 = (const float*)d_in[4];
    const float* wLH1 = (const float*)d_in[5];
    const float* wHL1 = (const float*)d_in[6];
    const float* wHH1 = (const float*)d_in[7];
    float* out = (float*)d_out;
    float* ws  = (float*)d_ws;

    const int S0 = 16 * 64 * 64 * 64;   // level-0 subband elems
    const int S1 = 16 * 32 * 32 * 64;   // level-1 subband elems

    // d_out doubles as scratch for the 4 level-0 subbands.
    float* c0LL = out;
    float* c0LH = out + 1 * S0;
    float* c0HL = out + 2 * S0;
    float* c0HH = out + 3 * S0;

    float* c1   = ws;                      // 4*S1, later reused as r1
    float* t0   = ws + 4 * S1;             // 3*S0
    float* t1   = ws + 4 * S1 + 3 * S0;    // 3*S1
    float* yA   = ws + 7 * S1 + 3 * S0;    // S1
    float* r1   = ws;                      // S0 == 4*S1, overwrites dead c1

    // 1) level-0 forward DWT: x (16,128,128,64) -> 4x (16,64,64,64)
    fwd_dwt<128><<<16 * 32 * 32 / 4, 256, 0, stream>>>(x, c0LL, c0LH, c0HL, c0HH);

    // 2) level-1 forward DWT: cLL0 -> 4x (16,32,32,64)
    fwd_dwt<64><<<16 * 16 * 16 / 4, 256, 0, stream>>>(c0LL,
        c1 + 0 * S1, c1 + 1 * S1, c1 + 2 * S1, c1 + 3 * S1);

    // 3) local conv level-0 details (Hd=Wd=64), 8 o per block
    local_conv<64, 4, 8><<<dim3(64, 8, 3), 256, 0, stream>>>(
        c0LH, c0HL, c0HH, nullptr,
        wLH0, wHL0, wHH0, nullptr,
        t0 + 0 * S0, t0 + 1 * S0, t0 + 2 * S0, nullptr);

    // 4) local conv level-1 (Hd=Wd=32): LH,HL,HH + LL (yA), 8 o per block
    local_conv<32, 2, 8><<<dim3(32, 8, 4), 256, 0, stream>>>(
        c1 + 1 * S1, c1 + 2 * S1, c1 + 3 * S1, c1 + 0 * S1,
        wLH1, wHL1, wHH1, wLL,
        t1 + 0 * S1, t1 + 1 * S1, t1 + 2 * S1, yA);

    // 5) inverse level-1: (yA, t1) -> r1 (16,64,64,64)
    inv_dwt<64><<<16 * 32 * 32 / 4, 256, 0, stream>>>(
        yA, t1 + 0 * S1, t1 + 1 * S1, t1 + 2 * S1, r1);

    // 6) inverse level-0: (r1, t0) -> out (16,128,128,64)
    inv_dwt<128><<<16 * 64 * 64 / 4, 256, 0, stream>>>(
        r1, t0 + 0 * S0, t0 + 1 * S0, t0 + 2 * S0, out);
}

// Round 4
// 291.054 us; speedup vs baseline: 1.3787x; 1.3787x over previous
//
#include <hip/hip_runtime.h>

// Analysis filters
__device__ __constant__ float H0[8] = { 0.0322231f, -0.01260397f, -0.09921954f,  0.2978578f,
                                        0.80373875f, 0.49761867f, -0.02963553f, -0.07576571f};
__device__ __constant__ float H1[8] = { 0.07576571f, -0.02963553f, -0.49761867f, 0.80373875f,
                                       -0.2978578f, -0.09921954f,  0.01260397f,  0.0322231f};
// Synthesis filters g0 = reverse(h0), g1 = reverse(h1)
__device__ __constant__ float G0[8] = {-0.07576571f, -0.02963553f,  0.49761867f, 0.80373875f,
                                        0.2978578f,  -0.09921954f, -0.01260397f, 0.0322231f};
__device__ __constant__ float G1[8] = { 0.0322231f,   0.01260397f, -0.09921954f, -0.2978578f,
                                        0.80373875f, -0.49761867f, -0.02963553f, 0.07576571f};

// ---------------------------------------------------------------------------
// Forward DWT, 2x2-output-tiled + separable (unchanged).
// ---------------------------------------------------------------------------
template<int HIN>
__global__ __launch_bounds__(256) void fwd_dwt(const float* __restrict__ in,
                                               float* __restrict__ oLL, float* __restrict__ oLH,
                                               float* __restrict__ oHL, float* __restrict__ oHH)
{
    constexpr int OH = HIN / 2;
    constexpr int TQ = OH / 2;
    const int tid = threadIdx.x;
    const int c = tid & 63;
    const int s = blockIdx.x * 4 + (tid >> 6);
    const int j = s % TQ;
    const int i = (s / TQ) % TQ;
    const int b = s / (TQ * TQ);

    float acc[2][2][4];
#pragma unroll
    for (int a = 0; a < 2; ++a)
#pragma unroll
        for (int d = 0; d < 2; ++d)
#pragma unroll
            for (int k = 0; k < 4; ++k) acc[a][d][k] = 0.f;

    const int iw0 = 4 * j - 3;
#pragma unroll
    for (int r = 0; r < 10; ++r) {
        const int ih = 4 * i + r - 3;
        if ((unsigned)ih < (unsigned)HIN) {
            const float* row = in + ((b * HIN + ih) * HIN) * 64 + c;
            float xv[10];
#pragma unroll
            for (int v = 0; v < 10; ++v) {
                const int iw = iw0 + v;
                xv[v] = ((unsigned)iw < (unsigned)HIN) ? row[iw * 64] : 0.f;
            }
            float h00 = 0.f, h01 = 0.f, h10 = 0.f, h11 = 0.f;
#pragma unroll
            for (int v = 0; v < 8; ++v) {
                h00 += H0[v] * xv[v];
                h10 += H1[v] * xv[v];
                h01 += H0[v] * xv[v + 2];
                h11 += H1[v] * xv[v + 2];
            }
#pragma unroll
            for (int ii = 0; ii < 2; ++ii) {
                const int u = r - 2 * ii;
                if (0 <= u && u < 8) {
                    const float a0 = H0[u], a1 = H1[u];
                    acc[ii][0][0] += a0 * h00;
                    acc[ii][0][1] += a0 * h10;
                    acc[ii][0][2] += a1 * h00;
                    acc[ii][0][3] += a1 * h10;
                    acc[ii][1][0] += a0 * h01;
                    acc[ii][1][1] += a0 * h11;
                    acc[ii][1][2] += a1 * h01;
                    acc[ii][1][3] += a1 * h11;
                }
            }
        }
    }

#pragma unroll
    for (int ii = 0; ii < 2; ++ii)
#pragma unroll
        for (int jj = 0; jj < 2; ++jj) {
            const int oh = 2 * i + ii, ow = 2 * j + jj;
            const int oidx = ((b * OH + oh) * OH + ow) * 64 + c;
            oLL[oidx] = acc[ii][jj][0];
            oLH[oidx] = acc[ii][jj][1];
            oHL[oidx] = acc[ii][jj][2];
            oHH[oidx] = acc[ii][jj][3];
        }
}

// ---------------------------------------------------------------------------
// Local conv v3: LDS-staged tile GEMM.
// out[b,h,w,o] = sum_i t[b,h,w,i] * W[i,o,w,h]   (W: [C][O][Wd][Hd], h innermost)
// Block = (h-tile of 16, w, z). i chunked by 4, staged in LDS:
//   Wl[ii][h][o] (o contiguous, row pad -> conflict-free float4 reads)
//   Al[ii][h][b] (b contiguous)
// Thread = (h, o4): owns 16 b x 4 o outputs. All global loads coalesced;
// weights/acts each read exactly once from HBM. Next chunk prefetched into
// registers before this chunk's FMAs (latency hidden under compute).
// ---------------------------------------------------------------------------
template<int HD>
__global__ __launch_bounds__(256) void local_conv_lds(
    const float* __restrict__ t0, const float* __restrict__ t1,
    const float* __restrict__ t2, const float* __restrict__ t3,
    const float* __restrict__ w0, const float* __restrict__ w1,
    const float* __restrict__ w2, const float* __restrict__ w3,
    float* __restrict__ o0, float* __restrict__ o1,
    float* __restrict__ o2, float* __restrict__ o3)
{
    constexpr int WH  = HD * HD;
    constexpr int HT  = 16;
    constexpr int RSW = 76;   // W row stride (floats): 64 o + 12 pad
    constexpr int RSA = 20;   // act row stride (floats): 16 b + 4 pad

    __shared__ __align__(16) float Wl[4][HT][RSW];
    __shared__ __align__(16) float Al[4][HT][RSA];

    const int z = blockIdx.z;
    const float* tin = (z == 0) ? t0 : (z == 1) ? t1 : (z == 2) ? t2 : t3;
    const float* wgt = (z == 0) ? w0 : (z == 1) ? w1 : (z == 2) ? w2 : w3;
    float*       out = (z == 0) ? o0 : (z == 1) ? o1 : (z == 2) ? o2 : o3;

    const int hbase = blockIdx.x * HT;
    const int w     = blockIdx.y;
    const int tid   = threadIdx.x;

    // staging roles
    const int so  = tid >> 2;        // 0..63 : o for W staging
    const int sh4 = tid & 3;         // 0..3  : h-quad for W staging
    const int sb  = tid >> 4;        // 0..15 : b for act staging
    const int sha = tid & 15;        // 0..15 : h for act staging

    // compute roles
    const int hc = tid & 15;         // h within tile
    const int o4 = tid >> 4;         // o-quad 0..15

    const float* wp0 = wgt + (so * WH) + w * HD + hbase + sh4 * 4;  // + (i*64)*WH per i
    const float* ap0 = tin + ((sb * HD + hbase + sha) * HD + w) * 64;

    float4 acc[16];
#pragma unroll
    for (int b = 0; b < 16; ++b) acc[b] = make_float4(0.f, 0.f, 0.f, 0.f);

    // prefetch chunk 0
    float4 wv[4], av;
#pragma unroll
    for (int r = 0; r < 4; ++r)
        wv[r] = *(const float4*)(wp0 + (size_t)(r * 64) * WH);
    av = *(const float4*)(ap0);

    for (int chunk = 0; chunk < 16; ++chunk) {
        __syncthreads();   // previous chunk's LDS reads complete
        // commit staged registers to LDS
#pragma unroll
        for (int r = 0; r < 4; ++r) {
            Wl[r][sh4 * 4 + 0][so] = wv[r].x;
            Wl[r][sh4 * 4 + 1][so] = wv[r].y;
            Wl[r][sh4 * 4 + 2][so] = wv[r].z;
            Wl[r][sh4 * 4 + 3][so] = wv[r].w;
        }
        Al[0][sha][sb] = av.x;
        Al[1][sha][sb] = av.y;
        Al[2][sha][sb] = av.z;
        Al[3][sha][sb] = av.w;
        __syncthreads();

        // prefetch next chunk (latency hides under FMAs below)
        if (chunk < 15) {
            const int i0n = (chunk + 1) * 4;
#pragma unroll
            for (int r = 0; r < 4; ++r)
                wv[r] = *(const float4*)(wp0 + (size_t)((i0n + r) * 64) * WH);
            av = *(const float4*)(ap0 + i0n);
        }

        // compute: acc[b][0..3] += Al[ii][hc][b] * Wl[ii][hc][o4*4..+3]
#pragma unroll
        for (int ii = 0; ii < 4; ++ii) {
            const float4 wf = *(const float4*)&Wl[ii][hc][o4 * 4];
#pragma unroll
            for (int bq = 0; bq < 4; ++bq) {
                const float4 af = *(const float4*)&Al[ii][hc][bq * 4];
                const float* afp = (const float*)&af;
#pragma unroll
                for (int k = 0; k < 4; ++k) {
                    const float a = afp[k];
                    acc[bq * 4 + k].x += a * wf.x;
                    acc[bq * 4 + k].y += a * wf.y;
                    acc[bq * 4 + k].z += a * wf.z;
                    acc[bq * 4 + k].w += a * wf.w;
                }
            }
        }
    }

#pragma unroll
    for (int b = 0; b < 16; ++b)
        *(float4*)(out + ((b * HD + hbase + hc) * HD + w) * 64 + o4 * 4) = acc[b];
}

// ---------------------------------------------------------------------------
// Inverse DWT, 2x2-output-tiled + separable (unchanged).
// ---------------------------------------------------------------------------
template<int HOUT>
__global__ __launch_bounds__(256) void inv_dwt(const float* __restrict__ yLL,
                                               const float* __restrict__ yLH,
                                               const float* __restrict__ yHL,
                                               const float* __restrict__ yHH,
                                               float* __restrict__ out)
{
    constexpr int HS = HOUT / 2;
    const int tid = threadIdx.x;
    const int c = tid & 63;
    const int s = blockIdx.x * 4 + (tid >> 6);
    const int j = s % HS;
    const int i = (s / HS) % HS;
    const int b = s / (HS * HS);

    float Pe[4] = {0.f, 0.f, 0.f, 0.f}, Po[4] = {0.f, 0.f, 0.f, 0.f};
    float Qe[4] = {0.f, 0.f, 0.f, 0.f}, Qo[4] = {0.f, 0.f, 0.f, 0.f};

#pragma unroll
    for (int ku = 0; ku < 4; ++ku) {
        const int m = i - 1 + ku;
        if ((unsigned)m < (unsigned)HS) {
            const float a0e = G0[1 + 2 * ku], a0o = G0[2 * ku];
            const float a1e = G1[1 + 2 * ku], a1o = G1[2 * ku];
            const int rowoff = (b * HS + m) * HS;
#pragma unroll
            for (int kv = 0; kv < 4; ++kv) {
                const int n = j - 1 + kv;
                if ((unsigned)n < (unsigned)HS) {
                    const int idx = (rowoff + n) * 64 + c;
                    const float yll = yLL[idx], ylh = yLH[idx];
                    const float yhl = yHL[idx], yhh = yHH[idx];
                    Pe[kv] += a0e * yll + a1e * yhl;
                    Po[kv] += a0o * yll + a1o * yhl;
                    Qe[kv] += a0e * ylh + a1e * yhh;
                    Qo[kv] += a0o * ylh + a1o * yhh;
                }
            }
        }
    }

    float o00 = 0.f, o01 = 0.f, o10 = 0.f, o11 = 0.f;
#pragma unroll
    for (int kv = 0; kv < 4; ++kv) {
        const float b0e = G0[1 + 2 * kv], b0o = G0[2 * kv];
        const float b1e = G1[1 + 2 * kv], b1o = G1[2 * kv];
        o00 += b0e * Pe[kv] + b1e * Qe[kv];
        o01 += b0o * Pe[kv] + b1o * Qe[kv];
        o10 += b0e * Po[kv] + b1e * Qo[kv];
        o11 += b0o * Po[kv] + b1o * Qo[kv];
    }

    const int h0 = 2 * i, w0 = 2 * j;
    const int base = ((b * HOUT + h0) * HOUT + w0) * 64 + c;
    out[base] = o00;
    out[base + 64] = o01;
    out[base + HOUT * 64] = o10;
    out[base + HOUT * 64 + 64] = o11;
}

// ---------------------------------------------------------------------------
extern "C" void kernel_launch(void* const* d_in, const int* in_sizes, int n_in,
                              void* d_out, int out_size, void* d_ws, size_t ws_size,
                              hipStream_t stream)
{
    const float* x    = (const float*)d_in[0];
    const float* wLL  = (const float*)d_in[1];
    const float* wLH0 = (const float*)d_in[2];
    const float* wHL0 = (const float*)d_in[3];
    const float* wHH0 = (const float*)d_in[4];
    const float* wLH1 = (const float*)d_in[5];
    const float* wHL1 = (const float*)d_in[6];
    const float* wHH1 = (const float*)d_in[7];
    float* out = (float*)d_out;
    float* ws  = (float*)d_ws;

    const int S0 = 16 * 64 * 64 * 64;   // level-0 subband elems
    const int S1 = 16 * 32 * 32 * 64;   // level-1 subband elems

    // d_out doubles as scratch for the 4 level-0 subbands.
    float* c0LL = out;
    float* c0LH = out + 1 * S0;
    float* c0HL = out + 2 * S0;
    float* c0HH = out + 3 * S0;

    float* c1   = ws;                      // 4*S1, later reused as r1
    float* t0   = ws + 4 * S1;             // 3*S0
    float* t1   = ws + 4 * S1 + 3 * S0;    // 3*S1
    float* yA   = ws + 7 * S1 + 3 * S0;    // S1
    float* r1   = ws;                      // S0 == 4*S1, overwrites dead c1

    // 1) level-0 forward DWT: x (16,128,128,64) -> 4x (16,64,64,64)
    fwd_dwt<128><<<16 * 32 * 32 / 4, 256, 0, stream>>>(x, c0LL, c0LH, c0HL, c0HH);

    // 2) level-1 forward DWT: cLL0 -> 4x (16,32,32,64)
    fwd_dwt<64><<<16 * 16 * 16 / 4, 256, 0, stream>>>(c0LL,
        c1 + 0 * S1, c1 + 1 * S1, c1 + 2 * S1, c1 + 3 * S1);

    // 3) local conv level-0 details (Hd=Wd=64): grid (hg=4, w=64, z=3)
    local_conv_lds<64><<<dim3(4, 64, 3), 256, 0, stream>>>(
        c0LH, c0HL, c0HH, nullptr,
        wLH0, wHL0, wHH0, nullptr,
        t0 + 0 * S0, t0 + 1 * S0, t0 + 2 * S0, nullptr);

    // 4) local conv level-1 (Hd=Wd=32): grid (hg=2, w=32, z=4)
    local_conv_lds<32><<<dim3(2, 32, 4), 256, 0, stream>>>(
        c1 + 1 * S1, c1 + 2 * S1, c1 + 3 * S1, c1 + 0 * S1,
        wLH1, wHL1, wHH1, wLL,
        t1 + 0 * S1, t1 + 1 * S1, t1 + 2 * S1, yA);

    // 5) inverse level-1: (yA, t1) -> r1 (16,64,64,64)
    inv_dwt<64><<<16 * 32 * 32 / 4, 256, 0, stream>>>(
        yA, t1 + 0 * S1, t1 + 1 * S1, t1 + 2 * S1, r1);

    // 6) inverse level-0: (r1, t0) -> out (16,128,128,64)
    inv_dwt<128><<<16 * 64 * 64 / 4, 256, 0, stream>>>(
        r1, t0 + 0 * S0, t0 + 1 * S0, t0 + 2 * S0, out);
}